// Round 1
// baseline (176.507 us; speedup 1.0000x reference)
//
#include <hip/hip_runtime.h>
#include <math.h>

#define B_   1024
#define L_   200
#define DIM_ 100
#define NP   128   // padded N (100 -> 128)
#define K_   1024

#define BM 16
#define KT 16
#define KC 128   // K per split-K chunk; grid.y = K_/KC = 8

// ---------------- Kernel 1: gather + mean-pool ----------------
// rel[b,d] = (sum_l emb_with_zero_row[items[b,l]][d]) / session_len[b]
// emb index 0 is the implicit zero row; idx>0 maps to item_embedding[idx-1].
__global__ __launch_bounds__(128) void gather_pool_k(
    const float* __restrict__ emb, const int* __restrict__ items,
    const float* __restrict__ slen, float* __restrict__ relP) {
  const int b = blockIdx.x;
  const int d = threadIdx.x;          // 0..127, 0..99 active
  const int* __restrict__ row = items + b * L_;
  if (d < DIM_) {
    float acc = 0.f;
    #pragma unroll 8
    for (int l = 0; l < L_; ++l) {
      const int idx = row[l];         // wave-uniform -> s_load
      if (idx > 0) acc += emb[(size_t)(idx - 1) * DIM_ + d];
    }
    relP[b * NP + d] = acc / slen[b];
  } else {
    relP[b * NP + d] = 0.f;           // zero padding cols 100..127
  }
}

// ---------------- Kernel 2/3: split-K GEMM, C += A_chunk @ B ----------------
// A: [1024][1024] row-major, Bm: [1024][NP], C: [1024][NP] (pre-zeroed)
__global__ __launch_bounds__(256) void gemm_splitk_k(
    const float* __restrict__ A,
    const float* __restrict__ Bm,
    float* __restrict__ C) {
  __shared__ float As[BM][KT];   // 16x16 = 1 KB
  __shared__ float Bs[KT][NP];   // 16x128 = 8 KB
  const int t   = threadIdx.x;
  const int m0  = blockIdx.x * BM;
  const int k0b = blockIdx.y * KC;
  const int tc  = t & 31;        // col group: cols tc*4 .. tc*4+3
  const int trg = t >> 5;        // 0..7 : rows trg*2, trg*2+1
  float acc[2][4] = {};

  for (int k0 = k0b; k0 < k0b + KC; k0 += KT) {
    // stage A tile: 256 floats, 1 per thread, coalesced 16-float row segments
    {
      const int r = t >> 4, kk = t & 15;
      As[r][kk] = A[(size_t)(m0 + r) * K_ + (k0 + kk)];
    }
    // stage B tile: 2048 floats, 8 per thread as 2x float4, fully coalesced
    {
      const int e = t * 4;
      const int r = e >> 7, c = e & 127;
      *(float4*)&Bs[r][c] = *(const float4*)&Bm[(size_t)(k0 + r) * NP + c];
      const int e2 = e + 1024;
      const int r2 = e2 >> 7, c2 = e2 & 127;
      *(float4*)&Bs[r2][c2] = *(const float4*)&Bm[(size_t)(k0 + r2) * NP + c2];
    }
    __syncthreads();

    #pragma unroll
    for (int kk4 = 0; kk4 < KT; kk4 += 4) {
      float a[2][4], bb[4][4];
      *(float4*)a[0] = *(const float4*)&As[trg * 2 + 0][kk4];   // broadcast reads
      *(float4*)a[1] = *(const float4*)&As[trg * 2 + 1][kk4];
      *(float4*)bb[0] = *(const float4*)&Bs[kk4 + 0][tc * 4];   // conflict-free b128
      *(float4*)bb[1] = *(const float4*)&Bs[kk4 + 1][tc * 4];
      *(float4*)bb[2] = *(const float4*)&Bs[kk4 + 2][tc * 4];
      *(float4*)bb[3] = *(const float4*)&Bs[kk4 + 3][tc * 4];
      #pragma unroll
      for (int j = 0; j < 4; ++j)
        #pragma unroll
        for (int r = 0; r < 2; ++r)
          #pragma unroll
          for (int c = 0; c < 4; ++c)
            acc[r][c] += a[r][j] * bb[j][c];
    }
    __syncthreads();
  }

  #pragma unroll
  for (int r = 0; r < 2; ++r)
    #pragma unroll
    for (int c = 0; c < 4; ++c)
      atomicAdd(&C[(size_t)(m0 + trg * 2 + r) * NP + (tc * 4 + c)], acc[r][c]);
}

// ---------------- Kernel 4: SELU + row L2-normalize ----------------
__global__ __launch_bounds__(128) void epilogue_k(
    const float* __restrict__ pre, float* __restrict__ out) {
  const int b = blockIdx.x, c = threadIdx.x;   // 128 threads, 100 valid cols
  const float x = pre[b * NP + c];
  const float scale = 1.0507009873554804934f;
  const float alpha = 1.6732632423543772848f;
  float s = (x > 0.f) ? (scale * x) : (scale * alpha * expm1f(x));
  if (c >= DIM_) s = 0.f;
  float ss = s * s;
  #pragma unroll
  for (int off = 32; off > 0; off >>= 1) ss += __shfl_down(ss, off, 64);
  __shared__ float wsum[2];
  if ((c & 63) == 0) wsum[c >> 6] = ss;
  __syncthreads();
  const float tot = wsum[0] + wsum[1];
  const float inv = 1.f / sqrtf(tot);
  if (c < DIM_) out[b * DIM_ + c] = s * inv;
}

extern "C" void kernel_launch(void* const* d_in, const int* in_sizes, int n_in,
                              void* d_out, int out_size, void* d_ws, size_t ws_size,
                              hipStream_t stream) {
  const float* emb   = (const float*)d_in[0];  // [50000][100]
  const int*   items = (const int*)d_in[1];    // [1024][200]
  const float* A     = (const float*)d_in[2];  // [1024][1024]
  const float* D     = (const float*)d_in[3];  // [1024][1024]
  const float* slen  = (const float*)d_in[4];  // [1024]
  float* out = (float*)d_out;                  // [1024][100]

  char* ws = (char*)d_ws;
  const size_t matB = (size_t)B_ * NP * sizeof(float);   // 512 KB
  float* relP = (float*)(ws);                  // [1024][128]
  float* tP   = (float*)(ws + matB);           // [1024][128]  (zeroed)
  float* preP = (float*)(ws + 2 * matB);       // [1024][128]  (zeroed)

  // zero the two atomic-accumulated buffers (ws is poisoned each call)
  hipMemsetAsync(tP, 0, 2 * matB, stream);

  gather_pool_k<<<B_, 128, 0, stream>>>(emb, items, slen, relP);
  // t = A @ rel   (reassociated: D@(A@rel) instead of (D@A)@rel -> 5x fewer FLOPs)
  gemm_splitk_k<<<dim3(B_ / BM, K_ / KC), 256, 0, stream>>>(A, relP, tP);
  // pre = D @ t
  gemm_splitk_k<<<dim3(B_ / BM, K_ / KC), 256, 0, stream>>>(D, tP, preP);
  epilogue_k<<<B_, 128, 0, stream>>>(preP, out);
}

// Round 2
// 175.410 us; speedup vs baseline: 1.0063x; 1.0063x over previous
//
#include <hip/hip_runtime.h>
#include <math.h>

#define B_   1024
#define L_   200
#define DIM_ 100
#define NP   128   // padded N (100 -> 128)
#define K_   1024

// ---------------- Kernel 1: gather + mean-pool (split-L, atomic combine) ----
// relP[b,d] += (sum_{l in chunk} emb0[items[b,l]][d]) / slen[b]
// emb index 0 is the implicit zero row; idx>0 maps to item_embedding[idx-1].
#define SPL  4            // L-chunks per b
#define LCH  (L_ / SPL)   // 50 items per chunk, 25 per l-stream
__global__ __launch_bounds__(256) void gather_pool_k(
    const float* __restrict__ emb, const int* __restrict__ items,
    const float* __restrict__ slen, float* __restrict__ relP) {
  const int b = blockIdx.x;
  const int t = threadIdx.x;
  const int s = t >> 7;            // l-stream 0/1 (wave-uniform)
  const int d = t & 127;           // dim 0..127 (100 valid)
  const int* __restrict__ row = items + b * L_ + blockIdx.y * LCH;
  float acc = 0.f;
  if (d < DIM_) {
    #pragma unroll
    for (int j = 0; j < LCH / 2; ++j) {
      const int idx = row[s + 2 * j];          // wave-uniform -> s_load
      if (idx > 0) acc += emb[(size_t)(idx - 1) * DIM_ + d];
    }
  }
  __shared__ float sm[128];
  if (s == 1) sm[d] = acc;
  __syncthreads();
  if (s == 0 && d < DIM_) {
    atomicAdd(&relP[b * NP + d], (acc + sm[d]) / slen[b]);
  }
}

// ---------------- Kernel 2/3: split-K GEMM, C += A_chunk @ B ----------------
// A: [1024][1024] row-major, Bm: [1024][NP], C: [1024][NP] (pre-zeroed)
#define BM 32
#define KT 16
#define KC 64    // grid.y = K_/KC = 16 chunks
__global__ __launch_bounds__(256) void gemm_splitk_k(
    const float* __restrict__ A,
    const float* __restrict__ Bm,
    float* __restrict__ C) {
  __shared__ float As[BM][KT];   // 32x16 = 2 KB
  __shared__ float Bs[KT][NP];   // 16x128 = 8 KB
  const int t   = threadIdx.x;
  const int m0  = blockIdx.x * BM;
  const int k0b = blockIdx.y * KC;
  const int tc  = t & 31;        // col group: cols tc*4 .. tc*4+3
  const int tr  = t >> 5;        // 0..7 : rows tr*4 .. tr*4+3
  float acc[4][4] = {};

  for (int k0 = k0b; k0 < k0b + KC; k0 += KT) {
    // stage A tile: 512 floats, threads 0..127 load one float4 each
    if (t < 128) {
      const int r = t >> 2, kk = (t & 3) * 4;
      *(float4*)&As[r][kk] = *(const float4*)&A[(size_t)(m0 + r) * K_ + (k0 + kk)];
    }
    // stage B tile: 2048 floats, 8 per thread as 2x float4, fully coalesced
    {
      const int e = t * 4;
      *(float4*)&Bs[e >> 7][e & 127] = *(const float4*)&Bm[(size_t)(k0 + (e >> 7)) * NP + (e & 127)];
      const int e2 = e + 1024;
      *(float4*)&Bs[e2 >> 7][e2 & 127] = *(const float4*)&Bm[(size_t)(k0 + (e2 >> 7)) * NP + (e2 & 127)];
    }
    __syncthreads();

    #pragma unroll
    for (int kk4 = 0; kk4 < KT; kk4 += 4) {
      float a[4][4], bb[4][4];
      #pragma unroll
      for (int i = 0; i < 4; ++i)      // A frag: 32-lane broadcast reads (free)
        *(float4*)a[i] = *(const float4*)&As[tr * 4 + i][kk4];
      #pragma unroll
      for (int j = 0; j < 4; ++j)      // B frag: conflict-free b128
        *(float4*)bb[j] = *(const float4*)&Bs[kk4 + j][tc * 4];
      #pragma unroll
      for (int j = 0; j < 4; ++j)
        #pragma unroll
        for (int i = 0; i < 4; ++i)
          #pragma unroll
          for (int c = 0; c < 4; ++c)
            acc[i][c] += a[i][j] * bb[j][c];
    }
    __syncthreads();
  }

  #pragma unroll
  for (int i = 0; i < 4; ++i)
    #pragma unroll
    for (int c = 0; c < 4; ++c)
      atomicAdd(&C[(size_t)(m0 + tr * 4 + i) * NP + (tc * 4 + c)], acc[i][c]);
}

// ---------------- Kernel 4: SELU + row L2-normalize ----------------
__global__ __launch_bounds__(128) void epilogue_k(
    const float* __restrict__ pre, float* __restrict__ out) {
  const int b = blockIdx.x, c = threadIdx.x;   // 128 threads, 100 valid cols
  const float x = pre[b * NP + c];
  const float scale = 1.0507009873554804934f;
  const float alpha = 1.6732632423543772848f;
  float s = (x > 0.f) ? (scale * x) : (scale * alpha * expm1f(x));
  if (c >= DIM_) s = 0.f;
  float ss = s * s;
  #pragma unroll
  for (int off = 32; off > 0; off >>= 1) ss += __shfl_down(ss, off, 64);
  __shared__ float wsum[2];
  if ((c & 63) == 0) wsum[c >> 6] = ss;
  __syncthreads();
  const float tot = wsum[0] + wsum[1];
  const float inv = 1.f / sqrtf(tot);
  if (c < DIM_) out[b * DIM_ + c] = s * inv;
}

extern "C" void kernel_launch(void* const* d_in, const int* in_sizes, int n_in,
                              void* d_out, int out_size, void* d_ws, size_t ws_size,
                              hipStream_t stream) {
  const float* emb   = (const float*)d_in[0];  // [50000][100]
  const int*   items = (const int*)d_in[1];    // [1024][200]
  const float* A     = (const float*)d_in[2];  // [1024][1024]
  const float* D     = (const float*)d_in[3];  // [1024][1024]
  const float* slen  = (const float*)d_in[4];  // [1024]
  float* out = (float*)d_out;                  // [1024][100]

  char* ws = (char*)d_ws;
  const size_t matB = (size_t)B_ * NP * sizeof(float);   // 512 KB
  float* relP = (float*)(ws);                  // [1024][128]  (zeroed, atomic)
  float* tP   = (float*)(ws + matB);           // [1024][128]  (zeroed, atomic)
  float* preP = (float*)(ws + 2 * matB);       // [1024][128]  (zeroed, atomic)

  // zero the three atomic-accumulated buffers (ws is poisoned each call)
  hipMemsetAsync(relP, 0, 3 * matB, stream);

  gather_pool_k<<<dim3(B_, SPL), 256, 0, stream>>>(emb, items, slen, relP);
  // t = A @ rel   (reassociated: D@(A@rel) instead of (D@A)@rel -> 5x fewer FLOPs)
  gemm_splitk_k<<<dim3(B_ / BM, K_ / KC), 256, 0, stream>>>(A, relP, tP);
  // pre = D @ t
  gemm_splitk_k<<<dim3(B_ / BM, K_ / KC), 256, 0, stream>>>(D, tP, preP);
  epilogue_k<<<B_, 128, 0, stream>>>(preP, out);
}

// Round 3
// 123.765 us; speedup vs baseline: 1.4262x; 1.4173x over previous
//
#include <hip/hip_runtime.h>
#include <math.h>

#define B_   1024
#define L_   200
#define DIM_ 100
#define NP   128   // padded N (100 -> 128)
#define K_   1024
#define NCH  8     // split-K chunks per GEMM

// ---------------- Kernel 1: gather + mean-pool (direct write, no atomics) ----
// relP[b,d] = (sum_l emb0[items[b,l]][d]) / slen[b]; emb idx 0 = zero row.
// 512 threads = 4 L-streams x 128 dims; LDS combine; 1024 blocks.
__global__ __launch_bounds__(512) void gather_pool_k(
    const float* __restrict__ emb, const int* __restrict__ items,
    const float* __restrict__ slen, float* __restrict__ relP) {
  const int b = blockIdx.x;
  const int t = threadIdx.x;
  const int s = t >> 7;            // L-stream 0..3 (wave-uniform)
  const int d = t & 127;           // dim 0..127 (100 valid)
  const int* __restrict__ row = items + b * L_ + s * (L_ / 4);  // 50 items
  float acc0 = 0.f, acc1 = 0.f;
  if (d < DIM_) {
    #pragma unroll
    for (int j = 0; j < L_ / 4; j += 2) {
      const int i0 = row[j];                   // wave-uniform -> s_load
      const int i1 = row[j + 1];
      if (i0 > 0) acc0 += emb[(size_t)(i0 - 1) * DIM_ + d];
      if (i1 > 0) acc1 += emb[(size_t)(i1 - 1) * DIM_ + d];
    }
  }
  __shared__ float sm[4][128];
  sm[s][d] = acc0 + acc1;
  __syncthreads();
  if (s == 0) {
    const float tot = sm[0][d] + sm[1][d] + sm[2][d] + sm[3][d];
    relP[b * NP + d] = (d < DIM_) ? tot / slen[b] : 0.f;
  }
}

// ---------------- Kernel 2/4: split-K GEMM -> private partial chunks --------
// A: [1024][1024] row-major, Bm: [1024][NP], Cpart: [NCH][1024][NP]
// chunk = blockIdx.y covers K rows [chunk*128, chunk*128+128)
#define BM 32
#define KT 16
__global__ __launch_bounds__(256) void gemm_splitk_k(
    const float* __restrict__ A,
    const float* __restrict__ Bm,
    float* __restrict__ Cpart) {
  __shared__ float As[BM][KT];   // 2 KB
  __shared__ float Bs[KT][NP];   // 8 KB
  const int t   = threadIdx.x;
  const int m0  = blockIdx.x * BM;
  const int k0b = blockIdx.y * (K_ / NCH);
  const int tc  = t & 31;        // col group: cols tc*4 .. tc*4+3
  const int tr  = t >> 5;        // 0..7 : rows tr*4 .. tr*4+3
  float acc[4][4] = {};

  for (int k0 = k0b; k0 < k0b + K_ / NCH; k0 += KT) {
    if (t < 128) {               // A tile: 512 floats, 128 x float4
      const int r = t >> 2, kk = (t & 3) * 4;
      *(float4*)&As[r][kk] = *(const float4*)&A[(size_t)(m0 + r) * K_ + (k0 + kk)];
    }
    {                            // B tile: 2048 floats, 2 x float4 per thread
      const int e = t * 4;
      *(float4*)&Bs[e >> 7][e & 127] = *(const float4*)&Bm[(size_t)(k0 + (e >> 7)) * NP + (e & 127)];
      const int e2 = e + 1024;
      *(float4*)&Bs[e2 >> 7][e2 & 127] = *(const float4*)&Bm[(size_t)(k0 + (e2 >> 7)) * NP + (e2 & 127)];
    }
    __syncthreads();

    #pragma unroll
    for (int kk4 = 0; kk4 < KT; kk4 += 4) {
      float a[4][4], bb[4][4];
      #pragma unroll
      for (int i = 0; i < 4; ++i)      // A frag: 32-lane broadcast (free)
        *(float4*)a[i] = *(const float4*)&As[tr * 4 + i][kk4];
      #pragma unroll
      for (int j = 0; j < 4; ++j)      // B frag: conflict-free b128
        *(float4*)bb[j] = *(const float4*)&Bs[kk4 + j][tc * 4];
      #pragma unroll
      for (int j = 0; j < 4; ++j)
        #pragma unroll
        for (int i = 0; i < 4; ++i)
          #pragma unroll
          for (int c = 0; c < 4; ++c)
            acc[i][c] += a[i][j] * bb[j][c];
    }
    __syncthreads();
  }

  float* Cc = Cpart + (size_t)blockIdx.y * B_ * NP;
  #pragma unroll
  for (int i = 0; i < 4; ++i)
    *(float4*)&Cc[(size_t)(m0 + tr * 4 + i) * NP + tc * 4] = *(float4*)acc[i];
}

// ---------------- Kernel 3: reduce 8 partial chunks -> t --------------------
__global__ __launch_bounds__(256) void reduce8_k(
    const float* __restrict__ part, float* __restrict__ outm) {
  const int i4 = blockIdx.x * 256 + threadIdx.x;       // float4 index, 32768 total
  const float4* p = (const float4*)part;
  float4 v = p[i4];
  #pragma unroll
  for (int c = 1; c < NCH; ++c) {
    float4 w = p[(size_t)c * (B_ * NP / 4) + i4];
    v.x += w.x; v.y += w.y; v.z += w.z; v.w += w.w;
  }
  ((float4*)outm)[i4] = v;
}

// ---------------- Kernel 5: sum partials + SELU + row L2-normalize ----------
__global__ __launch_bounds__(128) void epilogue_k(
    const float* __restrict__ prePart, float* __restrict__ out) {
  const int b = blockIdx.x, c = threadIdx.x;   // 128 threads, 100 valid cols
  float x = 0.f;
  #pragma unroll
  for (int p = 0; p < NCH; ++p)
    x += prePart[(size_t)p * B_ * NP + b * NP + c];
  const float scale = 1.0507009873554804934f;
  const float alpha = 1.6732632423543772848f;
  float s = (x > 0.f) ? (scale * x) : (scale * alpha * expm1f(x));
  if (c >= DIM_) s = 0.f;
  float ss = s * s;
  #pragma unroll
  for (int off = 32; off > 0; off >>= 1) ss += __shfl_down(ss, off, 64);
  __shared__ float wsum[2];
  if ((c & 63) == 0) wsum[c >> 6] = ss;
  __syncthreads();
  const float inv = 1.f / sqrtf(wsum[0] + wsum[1]);
  if (c < DIM_) out[b * DIM_ + c] = s * inv;
}

extern "C" void kernel_launch(void* const* d_in, const int* in_sizes, int n_in,
                              void* d_out, int out_size, void* d_ws, size_t ws_size,
                              hipStream_t stream) {
  const float* emb   = (const float*)d_in[0];  // [50000][100]
  const int*   items = (const int*)d_in[1];    // [1024][200]
  const float* A     = (const float*)d_in[2];  // [1024][1024]
  const float* D     = (const float*)d_in[3];  // [1024][1024]
  const float* slen  = (const float*)d_in[4];  // [1024]
  float* out = (float*)d_out;                  // [1024][100]

  char* ws = (char*)d_ws;
  const size_t matB = (size_t)B_ * NP * sizeof(float);   // 512 KB
  float* relP    = (float*)(ws);                          // [1024][128]
  float* tPart   = (float*)(ws + 1 * matB);               // [8][1024][128] = 4 MB
  float* tM      = (float*)(ws + 9 * matB);               // [1024][128]
  float* prePart = (float*)(ws + 10 * matB);              // [8][1024][128] = 4 MB

  // 1. rel = mean-pool(gather)      (no atomics, full overwrite)
  gather_pool_k<<<B_, 512, 0, stream>>>(emb, items, slen, relP);
  // 2. tPart[p] = A_chunk_p @ rel   (reassociated: D@(A@rel), 5x fewer FLOPs)
  gemm_splitk_k<<<dim3(B_ / BM, NCH), 256, 0, stream>>>(A, relP, tPart);
  // 3. t = sum_p tPart[p]
  reduce8_k<<<B_ * NP / 4 / 256, 256, 0, stream>>>(tPart, tM);
  // 4. prePart[p] = D_chunk_p @ t
  gemm_splitk_k<<<dim3(B_ / BM, NCH), 256, 0, stream>>>(D, tM, prePart);
  // 5. out = rownorm(selu(sum_p prePart[p]))
  epilogue_k<<<B_, 128, 0, stream>>>(prePart, out);
}

// Round 4
// 110.158 us; speedup vs baseline: 1.6023x; 1.1235x over previous
//
#include <hip/hip_runtime.h>
#include <math.h>

#define B_   1024
#define L_   200
#define DIM_ 100
#define NP   128   // padded N (100 -> 128)
#define K_   1024
#define NCH  16    // split-K chunks per GEMM
#define KCH  (K_ / NCH)   // 64 K-rows per chunk

// ---------------- Kernel 1: gather + mean-pool (float4 gathers) -------------
// relP[b,d] = (sum_l emb0[items[b,l]][d]) / slen[b]; emb idx 0 = zero row.
// Rows are 400 B = 25 aligned float4. 256 thr = 8 item-streams x 32 f4-cols.
__global__ __launch_bounds__(256) void gather_pool_k(
    const float* __restrict__ emb, const int* __restrict__ items,
    const float* __restrict__ slen, float4* __restrict__ relP4) {
  const int b = blockIdx.x;
  const int t = threadIdx.x;
  const int s = t >> 5;            // item stream 0..7
  const int c = t & 31;            // float4 col, valid c<25
  const int* __restrict__ row = items + b * L_;
  float4 acc = make_float4(0.f, 0.f, 0.f, 0.f);
  if (c < 25) {
    #pragma unroll
    for (int j = 0; j < L_ / 8; ++j) {         // 25 items per thread
      const int idx = row[s + 8 * j];
      if (idx > 0) {
        const float4 v = *(const float4*)&emb[(size_t)(idx - 1) * DIM_ + c * 4];
        acc.x += v.x; acc.y += v.y; acc.z += v.z; acc.w += v.w;
      }
    }
  }
  __shared__ float4 sm[8][32];                 // 4 KB
  sm[s][c] = acc;
  __syncthreads();
  if (s < 4) {
    float4 o = sm[s + 4][c];
    sm[s][c].x += o.x; sm[s][c].y += o.y; sm[s][c].z += o.z; sm[s][c].w += o.w;
  }
  __syncthreads();
  if (s < 2) {
    float4 o = sm[s + 2][c];
    sm[s][c].x += o.x; sm[s][c].y += o.y; sm[s][c].z += o.z; sm[s][c].w += o.w;
  }
  __syncthreads();
  if (s == 0) {
    float4 a0 = sm[0][c], a1 = sm[1][c];
    const float inv = 1.f / slen[b];
    float4 r;
    r.x = (a0.x + a1.x) * inv; r.y = (a0.y + a1.y) * inv;
    r.z = (a0.z + a1.z) * inv; r.w = (a0.w + a1.w) * inv;
    relP4[b * 32 + c] = (c < 25) ? r : make_float4(0.f, 0.f, 0.f, 0.f);
  }
}

// ---------------- Kernel 2/4: split-K GEMM -> private partial chunks --------
// A: [1024][1024] row-major, Bm: [1024][NP], Cpart: [NCH][1024][NP]
// One staging phase per block (whole 64-row K-chunk), one barrier.
#define BM 32
__global__ __launch_bounds__(256) void gemm_splitk_k(
    const float* __restrict__ A,
    const float* __restrict__ Bm,
    float* __restrict__ Cpart) {
  __shared__ float As[BM][KCH];   // 8 KB
  __shared__ float Bs[KCH][NP];   // 32 KB
  const int t   = threadIdx.x;
  const int m0  = blockIdx.x * BM;
  const int k0  = blockIdx.y * KCH;
  const int tc  = t & 31;        // col group: cols tc*4 .. tc*4+3
  const int tr  = t >> 5;        // 0..7 : rows tr*4 .. tr*4+3

  // stage A chunk: 2048 floats = 512 float4, 2 per thread
  #pragma unroll
  for (int q = 0; q < 2; ++q) {
    const int f = t + q * 256;            // 0..511
    const int r = f >> 4, kk = (f & 15) * 4;
    *(float4*)&As[r][kk] = *(const float4*)&A[(size_t)(m0 + r) * K_ + (k0 + kk)];
  }
  // stage B chunk: 8192 floats = 2048 float4, 8 per thread, coalesced
  #pragma unroll
  for (int q = 0; q < 8; ++q) {
    const int f = t + q * 256;            // 0..2047
    const int r = f >> 5, c = (f & 31) * 4;
    *(float4*)&Bs[r][c] = *(const float4*)&Bm[(size_t)(k0 + r) * NP + c];
  }
  __syncthreads();

  float acc[4][4] = {};
  #pragma unroll
  for (int kk4 = 0; kk4 < KCH; kk4 += 4) {
    float a[4][4], bb[4][4];
    #pragma unroll
    for (int i = 0; i < 4; ++i)      // A frag: 32-lane broadcast (free)
      *(float4*)a[i] = *(const float4*)&As[tr * 4 + i][kk4];
    #pragma unroll
    for (int j = 0; j < 4; ++j)      // B frag: consecutive-lane b128
      *(float4*)bb[j] = *(const float4*)&Bs[kk4 + j][tc * 4];
    #pragma unroll
    for (int j = 0; j < 4; ++j)
      #pragma unroll
      for (int i = 0; i < 4; ++i)
        #pragma unroll
        for (int c = 0; c < 4; ++c)
          acc[i][c] += a[i][j] * bb[j][c];
  }

  float* Cc = Cpart + (size_t)blockIdx.y * B_ * NP;
  #pragma unroll
  for (int i = 0; i < 4; ++i)
    *(float4*)&Cc[(size_t)(m0 + tr * 4 + i) * NP + tc * 4] = *(float4*)acc[i];
}

// ---------------- Kernel 3: reduce 16 partial chunks -> t -------------------
__global__ __launch_bounds__(256) void reduce_k(
    const float* __restrict__ part, float* __restrict__ outm) {
  const int i4 = blockIdx.x * 256 + threadIdx.x;       // float4 index, 32768
  const float4* p = (const float4*)part;
  float4 v = p[i4];
  #pragma unroll
  for (int c = 1; c < NCH; ++c) {
    float4 w = p[(size_t)c * (B_ * NP / 4) + i4];
    v.x += w.x; v.y += w.y; v.z += w.z; v.w += w.w;
  }
  ((float4*)outm)[i4] = v;
}

// ---------------- Kernel 5: sum partials + SELU + row L2-normalize ----------
__global__ __launch_bounds__(128) void epilogue_k(
    const float* __restrict__ prePart, float* __restrict__ out) {
  const int b = blockIdx.x, c = threadIdx.x;   // 128 threads, 100 valid cols
  float x = 0.f;
  #pragma unroll
  for (int p = 0; p < NCH; ++p)
    x += prePart[(size_t)p * B_ * NP + b * NP + c];
  const float scale = 1.0507009873554804934f;
  const float alpha = 1.6732632423543772848f;
  float s = (x > 0.f) ? (scale * x) : (scale * alpha * expm1f(x));
  if (c >= DIM_) s = 0.f;
  float ss = s * s;
  #pragma unroll
  for (int off = 32; off > 0; off >>= 1) ss += __shfl_down(ss, off, 64);
  __shared__ float wsum[2];
  if ((c & 63) == 0) wsum[c >> 6] = ss;
  __syncthreads();
  const float inv = 1.f / sqrtf(wsum[0] + wsum[1]);
  if (c < DIM_) out[b * DIM_ + c] = s * inv;
}

extern "C" void kernel_launch(void* const* d_in, const int* in_sizes, int n_in,
                              void* d_out, int out_size, void* d_ws, size_t ws_size,
                              hipStream_t stream) {
  const float* emb   = (const float*)d_in[0];  // [50000][100]
  const int*   items = (const int*)d_in[1];    // [1024][200]
  const float* A     = (const float*)d_in[2];  // [1024][1024]
  const float* D     = (const float*)d_in[3];  // [1024][1024]
  const float* slen  = (const float*)d_in[4];  // [1024]
  float* out = (float*)d_out;                  // [1024][100]

  char* ws = (char*)d_ws;
  const size_t matB = (size_t)B_ * NP * sizeof(float);   // 512 KB
  float* relP    = (float*)(ws);                          // [1024][128]
  float* tPart   = (float*)(ws + 1 * matB);               // [16][1024][128] = 8 MB
  float* tM      = (float*)(ws + 17 * matB);              // [1024][128]
  float* prePart = (float*)(ws + 18 * matB);              // [16][1024][128] = 8 MB

  // 1. rel = mean-pool(gather)      (float4 gathers, no atomics)
  gather_pool_k<<<B_, 256, 0, stream>>>(emb, items, slen, (float4*)relP);
  // 2. tPart[p] = A_chunk_p @ rel   (reassociated: D@(A@rel), 5x fewer FLOPs)
  gemm_splitk_k<<<dim3(B_ / BM, NCH), 256, 0, stream>>>(A, relP, tPart);
  // 3. t = sum_p tPart[p]
  reduce_k<<<B_ * NP / 4 / 256, 256, 0, stream>>>(tPart, tM);
  // 4. prePart[p] = D_chunk_p @ t
  gemm_splitk_k<<<dim3(B_ / BM, NCH), 256, 0, stream>>>(D, tM, prePart);
  // 5. out = rownorm(selu(sum_p prePart[p]))
  epilogue_k<<<B_, 128, 0, stream>>>(prePart, out);
}